// Round 10
// baseline (1698.694 us; speedup 1.0000x reference)
//
#include <hip/hip_runtime.h>

#define T_LEN 2048
#define D_IN  15
#define NTH   384

// per-seq region float offsets
#define OX    0                 // x chunk [128][16] (col 15 zero pad)
#define OHS   2048              // hs[2][128]: h1=0..59, h2=60..89, pad 90..127
                                // OHS%32==0 -> GSTEP 4-slice bank disjointness
#define ORG   2304              // ring [30][130] (h2 history, depth 128 + 2 pad)
#define RSZF  6208              // region floats (24832 B); seq1 = +RSZF
#define RSZB  (RSZF * 4)
#define OXB   (OX * 4)
#define OHSB  (OHS * 4)
#define ORGB  (ORG * 4)

typedef float f32x2 __attribute__((ext_vector_type(2)));

__device__ __forceinline__ float sig2(float x2) {   // 1/(1+2^x2)
    return __builtin_amdgcn_rcpf(1.0f + __builtin_amdgcn_exp2f(x2));
}
__device__ __forceinline__ float ftanh_(float x) {
    return 1.0f - 2.0f * __builtin_amdgcn_rcpf(
        __builtin_amdgcn_exp2f(x * 2.8853900817779268f) + 1.0f);
}

// quad_perm DPP cross-lane mov: VALU pipe, no LDS, no waitcnt.
// 0xB1 = [1,0,3,2] (xor1), 0x4E = [2,3,0,1] (xor2).
template<int CTRL>
__device__ __forceinline__ float dpp_mov(float v) {
    return __builtin_bit_cast(float,
        __builtin_amdgcn_update_dpp(0, __builtin_bit_cast(int, v),
                                    CTRL, 0xF, 0xF, true));
}

// one 16B slice, BOTH sequences: 2 ds_read_b128 + 16 pk-FMAs; every weight
// register feeds 2 FMAs (seqs share weights -> 2x ILP per lane).
#define GSTEP2(OFS, kk) do {                                        \
    float4 v0 = *(const float4*)(ldsb + (OFS));                     \
    float4 v1 = *(const float4*)(ldsb + (OFS) + RSZB);              \
    f32x2 v0l = {v0.x, v0.y}, v0h = {v0.z, v0.w};                   \
    f32x2 v1l = {v1.x, v1.y}, v1h = {v1.z, v1.w};                   \
    al0 = __builtin_elementwise_fma(v0l, wl[0][kk], al0);           \
    ah0 = __builtin_elementwise_fma(v0h, wh[0][kk], ah0);           \
    al1 = __builtin_elementwise_fma(v0l, wl[1][kk], al1);           \
    ah1 = __builtin_elementwise_fma(v0h, wh[1][kk], ah1);           \
    al2 = __builtin_elementwise_fma(v0l, wl[2][kk], al2);           \
    ah2 = __builtin_elementwise_fma(v0h, wh[2][kk], ah2);           \
    al3 = __builtin_elementwise_fma(v0l, wl[3][kk], al3);           \
    ah3 = __builtin_elementwise_fma(v0h, wh[3][kk], ah3);           \
    bl0 = __builtin_elementwise_fma(v1l, wl[0][kk], bl0);           \
    bh0 = __builtin_elementwise_fma(v1h, wh[0][kk], bh0);           \
    bl1 = __builtin_elementwise_fma(v1l, wl[1][kk], bl1);           \
    bh1 = __builtin_elementwise_fma(v1h, wh[1][kk], bh1);           \
    bl2 = __builtin_elementwise_fma(v1l, wl[2][kk], bl2);           \
    bh2 = __builtin_elementwise_fma(v1h, wh[2][kk], bh2);           \
    bl3 = __builtin_elementwise_fma(v1l, wl[3][kk], bl3);           \
    bh3 = __builtin_elementwise_fma(v1h, wh[3][kk], bh3);           \
} while (0)

#define ACC_DECL2                                                    \
    f32x2 al0={0.f,0.f}, al1={0.f,0.f}, al2={0.f,0.f}, al3={0.f,0.f},\
          ah0={0.f,0.f}, ah1={0.f,0.f}, ah2={0.f,0.f}, ah3={0.f,0.f},\
          bl0={0.f,0.f}, bl1={0.f,0.f}, bl2={0.f,0.f}, bl3={0.f,0.f},\
          bh0={0.f,0.f}, bh1={0.f,0.f}, bh2={0.f,0.f}, bh3={0.f,0.f};

// Accumulator j holds gate (q^j): reduce-scatter needs no selects.
// All cross-lane via quad_perm DPP (pure VALU, proven R9).
__device__ __forceinline__ void combine_act(
    f32x2 l0, f32x2 h0, f32x2 l1, f32x2 h1,
    f32x2 l2, f32x2 h2, f32x2 l3, f32x2 h3,
    float bias, float kneg, float mm, float cc,
    float& a, float& af, float& ag, float& ao)
{
    f32x2 t0 = l0 + h0;
    f32x2 t1 = l1 + h1;
    f32x2 t2 = l2 + h2;
    f32x2 t3 = l3 + h3;
    float p0 = t0.x + t0.y;
    float p1 = t1.x + t1.y;
    float p2 = t2.x + t2.y;
    float p3 = t3.x + t3.y;
    float A = p0 + dpp_mov<0xB1>(p1);
    float B = p2 + dpp_mov<0xB1>(p3);
    float S = A + dpp_mov<0x4E>(B);
    a  = fmaf(mm, sig2((S + bias) * kneg), cc);
    af = dpp_mov<0xB1>(a);   // q0 <- f
    ag = dpp_mov<0x4E>(a);   // q0 <- g
    ao = dpp_mov<0x4E>(af);  // q0 <- o
}

__global__ __launch_bounds__(NTH, 2) void lstm_fused(
    const float* __restrict__ x,
    const float* __restrict__ Wih1, const float* __restrict__ Whh1,
    const float* __restrict__ bih1, const float* __restrict__ bhh1,
    const float* __restrict__ Wih2, const float* __restrict__ Whh2,
    const float* __restrict__ bih2, const float* __restrict__ bhh2,
    const float* __restrict__ Wp,   const float* __restrict__ bp,
    float* __restrict__ out)
{
    __shared__ __align__(16) float lds[2 * RSZF];   // 49664 B
    __shared__ float wpls[32];

    const int tid = threadIdx.x;
    const int b   = blockIdx.x;
    const char* ldsb = (const char*)lds;

    const bool isL1 = (tid < 240);                  // waves 0-3 (3 is 3/4)
    const bool isL2 = (tid >= 256 && tid < 376);    // waves 4-5

    int u = 0, q = 0;
    if (isL1)      { u = tid >> 2;      q = tid & 3; }
    else if (isL2) { int l = tid - 256; u = l >> 2; q = l & 3; }

    f32x2 wl[4][6], wh[4][6];
    #pragma unroll
    for (int g = 0; g < 4; ++g)
        #pragma unroll
        for (int k = 0; k < 6; ++k) {
            wl[g][k] = (f32x2){0.f, 0.f};
            wh[g][k] = (f32x2){0.f, 0.f};
        }

    unsigned b0 = 0, b1 = 0, b2 = 0, b3 = 0, b4 = 0, b5 = 0, wb = 0, ringb = 0;
    float bias = 0.f, kneg = -1.4426950408889634f, mm = 1.f, cc = 0.f;
    float cst0 = 0.f, cst1 = 0.f;

    if (isL1) {
        // lane owns: quarter q of padded operand [x(16)|h1(60)|pad(4)];
        // accumulator g holds gate (q^g) of unit u, BOTH sequences.
        #pragma unroll
        for (int g = 0; g < 4; ++g) {
            const int r = (q ^ g) * 60 + u;
            #pragma unroll
            for (int k = 0; k < 5; ++k) {
                float e0[4];
                #pragma unroll
                for (int e = 0; e < 4; ++e) {
                    int j = q * 20 + k * 4 + e;
                    float val;
                    if (j < 15)      val = Wih1[r * 15 + j];
                    else if (j < 16) val = 0.f;                    // x pad
                    else if (j < 76) val = Whh1[r * 60 + (j - 16)];
                    else             val = 0.f;                    // h1 pad
                    e0[e] = val;
                }
                wl[g][k] = (f32x2){e0[0], e0[1]};
                wh[g][k] = (f32x2){e0[2], e0[3]};
            }
        }
        bias = bih1[q * 60 + u] + bhh1[q * 60 + u];
        if (q == 2) { kneg = -2.8853900817779268f; mm = 2.f; cc = -1.f; }
        if (q == 0) {
            b0 = OXB + 0;  b1 = OXB + 16;
            b2 = OXB + 32; b3 = OXB + 48;                 // x f4s (+xrow)
            b4 = OHSB + 0;                                 // h1[0..3] (+rb)
        } else {
            unsigned hb = OHSB + (unsigned)(q * 80 - 64);
            b0 = hb; b1 = hb + 16; b2 = hb + 32; b3 = hb + 48;  // (+rb)
            b4 = hb + 64;                                        // (+rb)
        }
        wb = OHSB + (unsigned)u * 4;
    } else if (isL2) {
        // operand = hs[0..95]: h1(60)|h2(30)|pad(6); quarter = 24 elems
        #pragma unroll
        for (int g = 0; g < 4; ++g) {
            const int r = (q ^ g) * 30 + u;
            #pragma unroll
            for (int k = 0; k < 6; ++k) {
                float e0[4];
                #pragma unroll
                for (int e = 0; e < 4; ++e) {
                    int j = q * 24 + k * 4 + e;
                    float val;
                    if (j < 60)      val = Wih2[r * 60 + j];
                    else if (j < 90) val = Whh2[r * 30 + (j - 60)];
                    else             val = 0.f;                   // pad
                    e0[e] = val;
                }
                wl[g][k] = (f32x2){e0[0], e0[1]};
                wh[g][k] = (f32x2){e0[2], e0[3]};
            }
        }
        bias = bih2[q * 30 + u] + bhh2[q * 30 + u];
        if (q == 2) { kneg = -2.8853900817779268f; mm = 2.f; cc = -1.f; }
        unsigned hb = OHSB + (unsigned)(q * 96);
        b0 = hb;      b1 = hb + 16; b2 = hb + 32;
        b3 = hb + 48; b4 = hb + 64; b5 = hb + 80;          // (+rb)
        wb    = OHSB + (unsigned)(60 + u) * 4;
        ringb = ORGB + (unsigned)u * 520;
    }

    // init: hs (both seqs, both buffers incl pads) = 0; x pad col = 0; Wp
    if (tid < 256) {
        lds[OHS + tid] = 0.f;
        lds[RSZF + OHS + tid] = 0.f;
        int ss = tid >> 7, tt = tid & 127;
        lds[ss * RSZF + OX + tt * 16 + 15] = 0.f;
    }
    if (tid < 30) wpls[tid] = Wp[tid];
    const float bpv = bp[0];
    __syncthreads();

    const float* xb = x + (size_t)b * 2 * T_LEN * D_IN;

    for (int t = 0; t <= T_LEN; ++t) {
        // ---- stage next 128 timesteps of x for both seqs (uniform) ----
        if ((t & 127) == 0 && t < T_LEN) {
            #pragma unroll
            for (int r5 = 0; r5 < 10; ++r5) {
                int i   = tid + r5 * NTH;        // 0..3839 exact
                int ss  = i / 1920;
                int rem = i - ss * 1920;
                int tt  = rem / 15;
                int dd  = rem - tt * 15;
                lds[ss * RSZF + OX + tt * 16 + dd] =
                    xb[(size_t)ss * T_LEN * D_IN + (size_t)t * D_IN + rem];
            }
            __syncthreads();
        }

        const unsigned rb   = (unsigned)(t & 1) << 9;   // read-buffer byte off
        const unsigned wbuf = rb ^ 512u;                // write-buffer byte off

        // ------------- gate compute + in-quad state update -------------
        if (isL1 && t < T_LEN) {
            const unsigned dyn = (q == 0) ? ((unsigned)(t & 127) << 6) : rb;
            ACC_DECL2;
            GSTEP2(b0 + dyn, 0); GSTEP2(b1 + dyn, 1); GSTEP2(b2 + dyn, 2);
            GSTEP2(b3 + dyn, 3); GSTEP2(b4 + rb, 4);
            float a0, af0, ag0, ao0, a1, af1, ag1, ao1;
            combine_act(al0, ah0, al1, ah1, al2, ah2, al3, ah3,
                        bias, kneg, mm, cc, a0, af0, ag0, ao0);
            combine_act(bl0, bh0, bl1, bh1, bl2, bh2, bl3, bh3,
                        bias, kneg, mm, cc, a1, af1, ag1, ao1);
            if (q == 0) {
                cst0 = fmaf(af0, cst0, a0 * ag0);
                *(float*)((char*)lds + (wb + wbuf)) = ao0 * ftanh_(cst0);
                cst1 = fmaf(af1, cst1, a1 * ag1);
                *(float*)((char*)lds + (wb + wbuf + RSZB)) = ao1 * ftanh_(cst1);
            }
        } else if (isL2 && t >= 1) {
            ACC_DECL2;
            GSTEP2(b0 + rb, 0); GSTEP2(b1 + rb, 1); GSTEP2(b2 + rb, 2);
            GSTEP2(b3 + rb, 3); GSTEP2(b4 + rb, 4); GSTEP2(b5 + rb, 5);
            float a0, af0, ag0, ao0, a1, af1, ag1, ao1;
            combine_act(al0, ah0, al1, ah1, al2, ah2, al3, ah3,
                        bias, kneg, mm, cc, a0, af0, ag0, ao0);
            combine_act(bl0, bh0, bl1, bh1, bl2, bh2, bl3, bh3,
                        bias, kneg, mm, cc, a1, af1, ag1, ao1);
            if (q == 0) {
                const unsigned rslot = (unsigned)(((t - 1) & 127) << 2);
                cst0 = fmaf(af0, cst0, a0 * ag0);
                float hv0 = ao0 * ftanh_(cst0);
                *(float*)((char*)lds + (wb + wbuf)) = hv0;
                *(float*)((char*)lds + (ringb + rslot)) = hv0;
                cst1 = fmaf(af1, cst1, a1 * ag1);
                float hv1 = ao1 * ftanh_(cst1);
                *(float*)((char*)lds + (wb + wbuf + RSZB)) = hv1;
                *(float*)((char*)lds + (ringb + rslot + RSZB)) = hv1;
            }
        }
        __syncthreads();   // h(t)/h2(t-1)/ring visible

        // ---- batched projection: 2 seqs x 64 outputs every 64 steps ----
        // ring depth 128: writers in iters t+1..t+64 touch the other half;
        // deeper skew blocked by the per-step barrier.
        if ((t & 63) == 0 && t >= 64 && tid < 128) {
            const int ss  = tid >> 6;
            const int col = tid & 63;
            const int sl  = ((t - 64) & 64) + col;
            const float* rg = lds + ss * RSZF + ORG;
            float p = bpv;
            #pragma unroll
            for (int k = 0; k < 30; ++k) p = fmaf(wpls[k], rg[k * 130 + sl], p);
            out[(size_t)(2 * b + ss) * T_LEN + (t - 64) + col] = p;
        }
    }
}

extern "C" void kernel_launch(void* const* d_in, const int* in_sizes, int n_in,
                              void* d_out, int out_size, void* d_ws, size_t ws_size,
                              hipStream_t stream) {
    const float* x    = (const float*)d_in[0];
    const float* Wih1 = (const float*)d_in[1];
    const float* Whh1 = (const float*)d_in[2];
    const float* bih1 = (const float*)d_in[3];
    const float* bhh1 = (const float*)d_in[4];
    const float* Wih2 = (const float*)d_in[5];
    const float* Whh2 = (const float*)d_in[6];
    const float* bih2 = (const float*)d_in[7];
    const float* bhh2 = (const float*)d_in[8];
    const float* Wp   = (const float*)d_in[9];
    const float* bp   = (const float*)d_in[10];

    int B = in_sizes[0] / (T_LEN * D_IN);   // 512
    int grid = B / 2;                        // 2 seqs/block = 256 blocks = #CUs

    lstm_fused<<<grid, NTH, 0, stream>>>(x, Wih1, Whh1, bih1, bhh1,
                                         Wih2, Whh2, bih2, bhh2,
                                         Wp, bp, (float*)d_out);
}

// Round 11
// 1374.474 us; speedup vs baseline: 1.2359x; 1.2359x over previous
//
#include <hip/hip_runtime.h>

#define T_LEN 2048
#define D_IN  15
#define NTH   768

// per-seq region float offsets
#define OX    0                 // x chunk [128][16] (col 15 zero pad)
#define OHS   2048              // hs[2][128]: h1=0..59, h2=60..89, pad 90..127
#define ORG   2304              // ring [30][130] (h2 history, depth 128 + 2 pad)
#define RSZF  6224              // region floats; 6224 % 32 == 16 -> seq1
                                // bank-staggered 16 vs seq0 (L1 conflict-free)
#define RSZB  (RSZF * 4)
#define OXB   (OX * 4)
#define OHSB  (OHS * 4)
#define ORGB  (ORG * 4)

typedef float f32x2 __attribute__((ext_vector_type(2)));

__device__ __forceinline__ float sig2(float x2) {   // 1/(1+2^x2)
    return __builtin_amdgcn_rcpf(1.0f + __builtin_amdgcn_exp2f(x2));
}
__device__ __forceinline__ float ftanh_(float x) {
    return 1.0f - 2.0f * __builtin_amdgcn_rcpf(
        __builtin_amdgcn_exp2f(x * 2.8853900817779268f) + 1.0f);
}

// Hot-loop barrier: LDS-only drain (no vmcnt) + raw s_barrier.
// __syncthreads() would also drain vmcnt(0), stalling on the projection's
// outstanding global stores and staging loads -- not needed for LDS
// producer/consumer correctness.
#define BAR_LGKM() do {                                             \
    asm volatile("s_waitcnt lgkmcnt(0)" ::: "memory");              \
    __builtin_amdgcn_s_barrier();                                   \
    asm volatile("" ::: "memory");                                  \
} while (0)

// quad_perm DPP cross-lane mov: VALU pipe, no LDS, no waitcnt.
// 0xB1 = [1,0,3,2] (xor1), 0x4E = [2,3,0,1] (xor2).
template<int CTRL>
__device__ __forceinline__ float dpp_mov(float v) {
    return __builtin_bit_cast(float,
        __builtin_amdgcn_update_dpp(0, __builtin_bit_cast(int, v),
                                    CTRL, 0xF, 0xF, true));
}

// one ds_read_b128 feeding 8 packed FMAs (4 gate rows x lo/hi)
#define GSTEP(OFS, kk) do {                                         \
    float4 v = *(const float4*)(ldsb + (OFS));                      \
    f32x2 vlo = {v.x, v.y};                                         \
    f32x2 vhi = {v.z, v.w};                                         \
    al0 = __builtin_elementwise_fma(vlo, wl[0][kk], al0);           \
    ah0 = __builtin_elementwise_fma(vhi, wh[0][kk], ah0);           \
    al1 = __builtin_elementwise_fma(vlo, wl[1][kk], al1);           \
    ah1 = __builtin_elementwise_fma(vhi, wh[1][kk], ah1);           \
    al2 = __builtin_elementwise_fma(vlo, wl[2][kk], al2);           \
    ah2 = __builtin_elementwise_fma(vhi, wh[2][kk], ah2);           \
    al3 = __builtin_elementwise_fma(vlo, wl[3][kk], al3);           \
    ah3 = __builtin_elementwise_fma(vhi, wh[3][kk], ah3);           \
} while (0)

// Accumulator j holds gate (q^j): reduce-scatter needs NO selects.
// A = gate q over quarters {q,q^1}; B = gate q^2 over {q,q^1};
// S = gate q over all quarters. Activate; gather f,g,o onto q0 lane.
// All cross-lane via quad_perm DPP (pure VALU, proven R9).
#define COMBINE_ACT()                                               \
    f32x2 t0 = al0 + ah0;                                           \
    f32x2 t1 = al1 + ah1;                                           \
    f32x2 t2 = al2 + ah2;                                           \
    f32x2 t3 = al3 + ah3;                                           \
    float p0 = t0.x + t0.y;                                         \
    float p1 = t1.x + t1.y;                                         \
    float p2 = t2.x + t2.y;                                         \
    float p3 = t3.x + t3.y;                                         \
    float A = p0 + dpp_mov<0xB1>(p1);                               \
    float B = p2 + dpp_mov<0xB1>(p3);                               \
    float S = A + dpp_mov<0x4E>(B);                                 \
    float a  = fmaf(mm, sig2((S + bias) * kneg), cc);               \
    float af = dpp_mov<0xB1>(a);   /* q0 <- f */                    \
    float ag = dpp_mov<0x4E>(a);   /* q0 <- g */                    \
    float ao = dpp_mov<0x4E>(af);  /* q0 <- o */

__global__ __launch_bounds__(NTH) void lstm_fused(
    const float* __restrict__ x,
    const float* __restrict__ Wih1, const float* __restrict__ Whh1,
    const float* __restrict__ bih1, const float* __restrict__ bhh1,
    const float* __restrict__ Wih2, const float* __restrict__ Whh2,
    const float* __restrict__ bih2, const float* __restrict__ bhh2,
    const float* __restrict__ Wp,   const float* __restrict__ bp,
    float* __restrict__ out)
{
    __shared__ __align__(16) float lds[2 * RSZF];   // 49792 B
    __shared__ float wpls[32];

    const int tid = threadIdx.x;
    const int b   = blockIdx.x;
    const char* ldsb = (const char*)lds;

    const bool isL1 = (tid < 480);                  // waves 0-7 (7 half idle)
    const bool isL2 = (tid >= 512 && tid < 752);    // waves 8-11

    // L2 waves are the per-step stragglers (6 GSTEPs + ring write vs L1's
    // 5): bump their issue priority so barrier arrivals compress (T5 with
    // genuine role diversity).
    if (tid >= 512) __builtin_amdgcn_s_setprio(1);

    int u = 0, s = 0, q = 0;
    if (isL1)      { u = tid >> 3;      s = (tid >> 2) & 1;          q = tid & 3; }
    else if (isL2) { int l = tid - 512; u = l >> 3; s = (l >> 2) & 1; q = l & 3; }
    const unsigned regB = (unsigned)s * RSZB;

    f32x2 wl[4][6], wh[4][6];
    #pragma unroll
    for (int g = 0; g < 4; ++g)
        #pragma unroll
        for (int k = 0; k < 6; ++k) {
            wl[g][k] = (f32x2){0.f, 0.f};
            wh[g][k] = (f32x2){0.f, 0.f};
        }

    unsigned b0 = 0, b1 = 0, b2 = 0, b3 = 0, b4 = 0, b5 = 0, wb = 0, ringb = 0;
    float bias = 0.f, kneg = -1.4426950408889634f, mm = 1.f, cc = 0.f;
    float cst = 0.f;

    if (isL1) {
        // lane owns: quarter q of padded operand [x(16)|h1(60)|pad(4)];
        // accumulator g holds gate (q^g) of unit u, sequence s.
        #pragma unroll
        for (int g = 0; g < 4; ++g) {
            const int r = (q ^ g) * 60 + u;
            #pragma unroll
            for (int k = 0; k < 5; ++k) {
                float e0[4];
                #pragma unroll
                for (int e = 0; e < 4; ++e) {
                    int j = q * 20 + k * 4 + e;
                    float val;
                    if (j < 15)      val = Wih1[r * 15 + j];
                    else if (j < 16) val = 0.f;                    // x pad
                    else if (j < 76) val = Whh1[r * 60 + (j - 16)];
                    else             val = 0.f;                    // h1 pad
                    e0[e] = val;
                }
                wl[g][k] = (f32x2){e0[0], e0[1]};
                wh[g][k] = (f32x2){e0[2], e0[3]};
            }
        }
        bias = bih1[q * 60 + u] + bhh1[q * 60 + u];
        if (q == 2) { kneg = -2.8853900817779268f; mm = 2.f; cc = -1.f; }
        if (q == 0) {
            b0 = regB + OXB + 0;  b1 = regB + OXB + 16;
            b2 = regB + OXB + 32; b3 = regB + OXB + 48;   // x f4s (+xrow)
            b4 = regB + OHSB + 0;                          // h1[0..3] (+rb)
        } else {
            unsigned hb = regB + OHSB + (unsigned)(q * 80 - 64);
            b0 = hb; b1 = hb + 16; b2 = hb + 32; b3 = hb + 48;  // (+rb)
            b4 = hb + 64;                                        // (+rb)
        }
        wb = regB + OHSB + (unsigned)u * 4;
    } else if (isL2) {
        // operand = hs[0..95]: h1(60)|h2(30)|pad(6); quarter = 24 elems.
        // seq1 lanes read their 6 slices rotated by 3 ((k+3)%6): bank-
        // disjoint from seq0 within every GSTEP instruction.
        #pragma unroll
        for (int g = 0; g < 4; ++g) {
            const int r = (q ^ g) * 30 + u;
            #pragma unroll
            for (int k = 0; k < 6; ++k) {
                const int jb = (k + 3 * s) % 6;      // slice index for slot k
                float e0[4];
                #pragma unroll
                for (int e = 0; e < 4; ++e) {
                    int j = q * 24 + jb * 4 + e;
                    float val;
                    if (j < 60)      val = Wih2[r * 60 + j];
                    else if (j < 90) val = Whh2[r * 30 + (j - 60)];
                    else             val = 0.f;                   // pad
                    e0[e] = val;
                }
                wl[g][k] = (f32x2){e0[0], e0[1]};
                wh[g][k] = (f32x2){e0[2], e0[3]};
            }
        }
        bias = bih2[q * 30 + u] + bhh2[q * 30 + u];
        if (q == 2) { kneg = -2.8853900817779268f; mm = 2.f; cc = -1.f; }
        unsigned hb = regB + OHSB + (unsigned)(q * 96);
        const int r3 = 3 * s;
        b0 = hb + (unsigned)(((0 + r3) % 6) * 16);
        b1 = hb + (unsigned)(((1 + r3) % 6) * 16);
        b2 = hb + (unsigned)(((2 + r3) % 6) * 16);
        b3 = hb + (unsigned)(((3 + r3) % 6) * 16);
        b4 = hb + (unsigned)(((4 + r3) % 6) * 16);
        b5 = hb + (unsigned)(((5 + r3) % 6) * 16);      // (+rb at use)
        wb    = regB + OHSB + (unsigned)(60 + u) * 4;
        ringb = regB + ORGB + (unsigned)u * 520;
    }

    // init: hs (both buffers incl pads) = 0; x pad column = 0; Wp staged
    if (tid < 512) { int ss = tid >> 8; int i = tid & 255; lds[ss * RSZF + OHS + i] = 0.f; }
    else           { int i = tid - 512; int ss = i >> 7;   lds[ss * RSZF + OX + (i & 127) * 16 + 15] = 0.f; }
    if (tid < 30) wpls[tid] = Wp[tid];
    const float bpv = bp[0];
    __syncthreads();

    const float* xb = x + (size_t)b * 2 * T_LEN * D_IN;

    for (int t = 0; t <= T_LEN; ++t) {
        // ---- stage next 128 timesteps of x for both seqs (uniform) ----
        if ((t & 127) == 0 && t < T_LEN) {
            #pragma unroll
            for (int r5 = 0; r5 < 5; ++r5) {
                int i   = tid + r5 * NTH;        // 0..3839 exact
                int ss  = i / 1920;
                int rem = i - ss * 1920;
                int tt  = rem / 15;
                int dd  = rem - tt * 15;
                lds[ss * RSZF + OX + tt * 16 + dd] =
                    xb[(size_t)ss * T_LEN * D_IN + (size_t)t * D_IN + rem];
            }
            BAR_LGKM();
        }

        const unsigned rb   = (unsigned)(t & 1) << 9;   // read-buffer byte off
        const unsigned wbuf = rb ^ 512u;                // write-buffer byte off

        // ------------- gate compute + in-quad state update -------------
        if (isL1 && t < T_LEN) {
            const unsigned dyn = (q == 0) ? ((unsigned)(t & 127) << 6) : rb;
            f32x2 al0 = {0.f,0.f}, al1 = {0.f,0.f}, al2 = {0.f,0.f}, al3 = {0.f,0.f};
            f32x2 ah0 = {0.f,0.f}, ah1 = {0.f,0.f}, ah2 = {0.f,0.f}, ah3 = {0.f,0.f};
            GSTEP(b0 + dyn, 0); GSTEP(b1 + dyn, 1); GSTEP(b2 + dyn, 2);
            GSTEP(b3 + dyn, 3); GSTEP(b4 + rb, 4);
            COMBINE_ACT();
            if (q == 0) {
                cst = fmaf(af, cst, a * ag);
                *(float*)((char*)lds + (wb + wbuf)) = ao * ftanh_(cst);
            }
        } else if (isL2 && t >= 1) {
            f32x2 al0 = {0.f,0.f}, al1 = {0.f,0.f}, al2 = {0.f,0.f}, al3 = {0.f,0.f};
            f32x2 ah0 = {0.f,0.f}, ah1 = {0.f,0.f}, ah2 = {0.f,0.f}, ah3 = {0.f,0.f};
            GSTEP(b0 + rb, 0); GSTEP(b1 + rb, 1); GSTEP(b2 + rb, 2);
            GSTEP(b3 + rb, 3); GSTEP(b4 + rb, 4); GSTEP(b5 + rb, 5);
            COMBINE_ACT();
            if (q == 0) {
                cst = fmaf(af, cst, a * ag);
                float hv = ao * ftanh_(cst);
                *(float*)((char*)lds + (wb + wbuf)) = hv;
                *(float*)((char*)lds + (ringb + (unsigned)(((t - 1) & 127) << 2))) = hv;
            }
        }
        BAR_LGKM();   // h(t)/h2(t-1)/ring visible; LDS-only drain

        // ---- batched projection: 2 seqs x 64 outputs every 64 steps ----
        // ring depth 128: writers in iters t+1..t+64 touch the other half;
        // deeper skew blocked by the per-step barrier.
        if ((t & 63) == 0 && t >= 64 && tid < 128) {
            const int ss  = tid >> 6;
            const int col = tid & 63;
            const int sl  = ((t - 64) & 64) + col;
            const float* rg = lds + ss * RSZF + ORG;
            float p = bpv;
            #pragma unroll
            for (int k = 0; k < 30; ++k) p = fmaf(wpls[k], rg[k * 130 + sl], p);
            out[(size_t)(2 * b + ss) * T_LEN + (t - 64) + col] = p;
        }
    }
}

extern "C" void kernel_launch(void* const* d_in, const int* in_sizes, int n_in,
                              void* d_out, int out_size, void* d_ws, size_t ws_size,
                              hipStream_t stream) {
    const float* x    = (const float*)d_in[0];
    const float* Wih1 = (const float*)d_in[1];
    const float* Whh1 = (const float*)d_in[2];
    const float* bih1 = (const float*)d_in[3];
    const float* bhh1 = (const float*)d_in[4];
    const float* Wih2 = (const float*)d_in[5];
    const float* Whh2 = (const float*)d_in[6];
    const float* bih2 = (const float*)d_in[7];
    const float* bhh2 = (const float*)d_in[8];
    const float* Wp   = (const float*)d_in[9];
    const float* bp   = (const float*)d_in[10];

    int B = in_sizes[0] / (T_LEN * D_IN);   // 512
    int grid = B / 2;                        // 2 seqs/block = 256 blocks = #CUs

    lstm_fused<<<grid, NTH, 0, stream>>>(x, Wih1, Whh1, bih1, bhh1,
                                         Wih2, Whh2, bih2, bhh2,
                                         Wp, bp, (float*)d_out);
}